// Round 1
// baseline (48.821 us; speedup 1.0000x reference)
//
#include <hip/hip_runtime.h>
#include <math.h>

#define NB 2
#define NN 512
#define DD 128

__device__ __forceinline__ float fast_silu(float x) {
    // x * sigmoid(x) = x / (1 + exp(-x)); denom >= 1 so fast rcp is safe.
    float e = __expf(-x);
    return x * __builtin_amdgcn_rcpf(1.0f + e);
}

// ---------------------------------------------------------------------------
// Kernel A: per-node GEMVs.
//  scalar_out[b,i,:] = silu(nf@Ws1+bs1)@Ws2+bs2        (written to d_out)
//  base_out[b,i,:]   = nf@Wa1[:128,:]+ba1              (workspace)
//  vf3_out[b,i,0:3]  = (silu(nf@Wv1+bv1)@Wv2+bv2)[0:3] (workspace)
// 4 rows per block (register blocking amortizes weight reads through L2).
// ---------------------------------------------------------------------------
__global__ __launch_bounds__(128) void k_node(
    const float* __restrict__ nf,
    const float* __restrict__ Ws1, const float* __restrict__ bs1,
    const float* __restrict__ Ws2, const float* __restrict__ bs2,
    const float* __restrict__ Wv1, const float* __restrict__ bv1,
    const float* __restrict__ Wv2, const float* __restrict__ bv2,
    const float* __restrict__ Wa1, const float* __restrict__ ba1,
    float* __restrict__ scalar_out,
    float* __restrict__ base_out,
    float* __restrict__ vf3_out)
{
    const int ROWS = 4;
    __shared__ float sNF[ROWS][DD];
    __shared__ float sH[ROWS][DD];
    const int t  = threadIdx.x;
    const int r0 = blockIdx.x * ROWS;

    #pragma unroll
    for (int r = 0; r < ROWS; ++r) sNF[r][t] = nf[(r0 + r) * DD + t];
    __syncthreads();

    float acc[ROWS];

    // ---- scalar branch: hidden ----
    {
        float b = bs1[t];
        #pragma unroll
        for (int r = 0; r < ROWS; ++r) acc[r] = b;
        for (int k = 0; k < DD; ++k) {
            float w = Ws1[k * DD + t];
            #pragma unroll
            for (int r = 0; r < ROWS; ++r) acc[r] += sNF[r][k] * w;
        }
        #pragma unroll
        for (int r = 0; r < ROWS; ++r) sH[r][t] = fast_silu(acc[r]);
    }
    __syncthreads();
    // ---- scalar branch: output ----
    {
        float b = bs2[t];
        #pragma unroll
        for (int r = 0; r < ROWS; ++r) acc[r] = b;
        for (int k = 0; k < DD; ++k) {
            float w = Ws2[k * DD + t];
            #pragma unroll
            for (int r = 0; r < ROWS; ++r) acc[r] += sH[r][k] * w;
        }
        #pragma unroll
        for (int r = 0; r < ROWS; ++r) scalar_out[(r0 + r) * DD + t] = acc[r];
    }
    __syncthreads();
    // ---- vector branch: hidden ----
    {
        float b = bv1[t];
        #pragma unroll
        for (int r = 0; r < ROWS; ++r) acc[r] = b;
        for (int k = 0; k < DD; ++k) {
            float w = Wv1[k * DD + t];
            #pragma unroll
            for (int r = 0; r < ROWS; ++r) acc[r] += sNF[r][k] * w;
        }
        #pragma unroll
        for (int r = 0; r < ROWS; ++r) sH[r][t] = fast_silu(acc[r]);
    }
    __syncthreads();
    // ---- vector branch: only output columns 0..2 are ever used ----
    if (t < ROWS * 3) {
        int r = t / 3, c = t % 3;
        float a = bv2[c];
        for (int k = 0; k < DD; ++k) a += sH[r][k] * Wv2[k * DD + c];
        vf3_out[(r0 + r) * 3 + c] = a;
    }
    // ---- attention base: nf @ Wa1[:128,:] + ba1 (reads only sNF; no race) ----
    {
        float b = ba1[t];
        #pragma unroll
        for (int r = 0; r < ROWS; ++r) acc[r] = b;
        for (int k = 0; k < DD; ++k) {
            float w = Wa1[k * DD + t];
            #pragma unroll
            for (int r = 0; r < ROWS; ++r) acc[r] += sNF[r][k] * w;
        }
        #pragma unroll
        for (int r = 0; r < ROWS; ++r) base_out[(r0 + r) * DD + t] = acc[r];
    }
}

// ---------------------------------------------------------------------------
// Kernel B: one block per (b,i) row. 256 threads, 2 j's per thread.
// logit_ij = ba2 + sum_t silu(base_i[t] + d*w0[t] + dinv*w1[t] + dexp*w2[t]) * Wa2[t]
// then masked softmax over j and aggregation of e_ij * (x_i - x_j).
// ---------------------------------------------------------------------------
__global__ __launch_bounds__(256) void k_attn(
    const float* __restrict__ coords,
    const int*   __restrict__ mask,
    const float* __restrict__ Wa1,
    const float* __restrict__ Wa2,
    const float* __restrict__ ba2p,
    const float* __restrict__ base,
    const float* __restrict__ vf3,
    float* __restrict__ vec_out)
{
    __shared__ float s_base[DD], s_w0[DD], s_w1[DD], s_w2[DD], s_a2[DD];
    __shared__ float s_r[4][256];

    const int row = blockIdx.x;          // b*NN + i
    const int b   = row >> 9;
    const int tid = threadIdx.x;

    if (tid < DD) {
        s_base[tid] = base[row * DD + tid];
        s_w0[tid]   = Wa1[128 * DD + tid];   // row for 'distances'
        s_w1[tid]   = Wa1[129 * DD + tid];   // row for 1/(d+1e-6)
        s_w2[tid]   = Wa1[130 * DD + tid];   // row for exp(-d)
        s_a2[tid]   = Wa2[tid];
    }
    __syncthreads();

    const float ba2 = ba2p[0];
    const float xi0 = coords[row * 3 + 0];
    const float xi1 = coords[row * 3 + 1];
    const float xi2 = coords[row * 3 + 2];
    const float* cb   = coords + (size_t)b * NN * 3;
    const int*   mrow = mask + (size_t)row * NN;

    float lg[2];
    int   mk[2];
    float lmax = -__builtin_inff();

    const float4* b4 = (const float4*)s_base;
    const float4* q0 = (const float4*)s_w0;
    const float4* q1 = (const float4*)s_w1;
    const float4* q2 = (const float4*)s_w2;
    const float4* qa = (const float4*)s_a2;

    #pragma unroll
    for (int s = 0; s < 2; ++s) {
        const int j = tid + s * 256;
        mk[s] = mrow[j];
        float dx = xi0 - cb[j * 3 + 0];
        float dy = xi1 - cb[j * 3 + 1];
        float dz = xi2 - cb[j * 3 + 2];
        float d2 = dx * dx + dy * dy + dz * dz;
        float d  = (d2 > 0.0f) ? sqrtf(d2) : 0.0f;
        float f1 = d;
        float f2 = 1.0f / (d + 1e-6f);   // exact div: can be ~1e6, once per pair
        float f3 = __expf(-d);

        float acc = ba2;
        #pragma unroll 4
        for (int t4 = 0; t4 < DD / 4; ++t4) {
            float4 bb = b4[t4], p0 = q0[t4], p1 = q1[t4], p2 = q2[t4], aa = qa[t4];
            { float pre = bb.x + f1 * p0.x + f2 * p1.x + f3 * p2.x; acc += fast_silu(pre) * aa.x; }
            { float pre = bb.y + f1 * p0.y + f2 * p1.y + f3 * p2.y; acc += fast_silu(pre) * aa.y; }
            { float pre = bb.z + f1 * p0.z + f2 * p1.z + f3 * p2.z; acc += fast_silu(pre) * aa.z; }
            { float pre = bb.w + f1 * p0.w + f2 * p1.w + f3 * p2.w; acc += fast_silu(pre) * aa.w; }
        }
        lg[s] = mk[s] ? acc : -__builtin_inff();
        lmax  = fmaxf(lmax, lg[s]);
    }

    // ---- block max reduction ----
    s_r[0][tid] = lmax;
    __syncthreads();
    for (int ofs = 128; ofs >= 1; ofs >>= 1) {
        if (tid < ofs) s_r[0][tid] = fmaxf(s_r[0][tid], s_r[0][tid + ofs]);
        __syncthreads();
    }
    const float mx = s_r[0][0];
    __syncthreads();

    // ---- exp + weighted diff accumulation ----
    float esum = 0.0f, wx = 0.0f, wy = 0.0f, wz = 0.0f;
    #pragma unroll
    for (int s = 0; s < 2; ++s) {
        const int j = tid + s * 256;
        if (mk[s]) {
            float e  = __expf(lg[s] - mx);
            float dx = xi0 - cb[j * 3 + 0];
            float dy = xi1 - cb[j * 3 + 1];
            float dz = xi2 - cb[j * 3 + 2];
            esum += e; wx += e * dx; wy += e * dy; wz += e * dz;
        }
    }
    s_r[0][tid] = esum; s_r[1][tid] = wx; s_r[2][tid] = wy; s_r[3][tid] = wz;
    __syncthreads();
    for (int ofs = 128; ofs >= 1; ofs >>= 1) {
        if (tid < ofs) {
            s_r[0][tid] += s_r[0][tid + ofs];
            s_r[1][tid] += s_r[1][tid + ofs];
            s_r[2][tid] += s_r[2][tid + ofs];
            s_r[3][tid] += s_r[3][tid + ofs];
        }
        __syncthreads();
    }
    if (tid < 3) {
        float inv = 1.0f / s_r[0][0];
        float va  = s_r[1 + tid][0] * inv;            // vector_aggregated[c]
        vec_out[row * 3 + tid] = va * vf3[row * 3 + tid];
    }
}

extern "C" void kernel_launch(void* const* d_in, const int* in_sizes, int n_in,
                              void* d_out, int out_size, void* d_ws, size_t ws_size,
                              hipStream_t stream) {
    const float* nf     = (const float*)d_in[0];
    const float* coords = (const float*)d_in[1];
    const int*   mask   = (const int*)  d_in[2];
    const float* Ws1 = (const float*)d_in[3];  const float* bs1 = (const float*)d_in[4];
    const float* Ws2 = (const float*)d_in[5];  const float* bs2 = (const float*)d_in[6];
    const float* Wv1 = (const float*)d_in[7];  const float* bv1 = (const float*)d_in[8];
    const float* Wv2 = (const float*)d_in[9];  const float* bv2 = (const float*)d_in[10];
    const float* Wa1 = (const float*)d_in[11]; const float* ba1 = (const float*)d_in[12];
    const float* Wa2 = (const float*)d_in[13]; const float* ba2 = (const float*)d_in[14];

    float* scalar_out = (float*)d_out;                       // [NB*NN*DD]
    float* vec_out    = (float*)d_out + NB * NN * DD;        // [NB*NN*3]
    float* base_ws    = (float*)d_ws;                        // [NB*NN*DD]
    float* vf3_ws     = (float*)d_ws + NB * NN * DD;         // [NB*NN*3]

    hipLaunchKernelGGL(k_node, dim3(NB * NN / 4), dim3(128), 0, stream,
                       nf, Ws1, bs1, Ws2, bs2, Wv1, bv1, Wv2, bv2, Wa1, ba1,
                       scalar_out, base_ws, vf3_ws);
    hipLaunchKernelGGL(k_attn, dim3(NB * NN), dim3(256), 0, stream,
                       coords, mask, Wa1, Wa2, ba2, base_ws, vf3_ws, vec_out);
}

// Round 2
// 36.217 us; speedup vs baseline: 1.3480x; 1.3480x over previous
//
#include <hip/hip_runtime.h>
#include <math.h>

#define NB 2
#define NN 512
#define DD 128
#define LOG2E 1.4426950408889634f

__device__ __forceinline__ float exp2_hw(float x) {
    float r; asm("v_exp_f32 %0, %1" : "=v"(r) : "v"(x)); return r;
}
__device__ __forceinline__ float silu_f(float x) {
    float e = exp2_hw(-LOG2E * x);
    return x * __builtin_amdgcn_rcpf(1.0f + e);
}

// ---------------------------------------------------------------------------
// Kernel A: per-node GEMVs, 4 rows per block, 128 threads (one output col each).
// Layer-1 fused across the 3 matrices (Ws1, Wv1, Wa1) so the float4 LDS
// broadcast of nf amortizes over 12 FMAs.
// ---------------------------------------------------------------------------
__global__ __launch_bounds__(128) void k_node(
    const float* __restrict__ nf,
    const float* __restrict__ Ws1, const float* __restrict__ bs1,
    const float* __restrict__ Ws2, const float* __restrict__ bs2,
    const float* __restrict__ Wv1, const float* __restrict__ bv1,
    const float* __restrict__ Wv2, const float* __restrict__ bv2,
    const float* __restrict__ Wa1, const float* __restrict__ ba1,
    float* __restrict__ scalar_out,
    float* __restrict__ base_out,
    float* __restrict__ vf3_out)
{
    __shared__ float4 sNF[DD];   // (row0..row3) packed per feature k
    __shared__ float4 sHs[DD];   // scalar-branch hidden, packed
    __shared__ float4 sHv[DD];   // vector-branch hidden, packed
    const int t  = threadIdx.x;
    const int r0 = blockIdx.x * 4;

    {
        float4 v;
        v.x = nf[(r0 + 0) * DD + t];
        v.y = nf[(r0 + 1) * DD + t];
        v.z = nf[(r0 + 2) * DD + t];
        v.w = nf[(r0 + 3) * DD + t];
        sNF[t] = v;
    }
    __syncthreads();

    float4 as, av, aa;
    { float b = bs1[t]; as = make_float4(b, b, b, b); }
    { float b = bv1[t]; av = make_float4(b, b, b, b); }
    { float b = ba1[t]; aa = make_float4(b, b, b, b); }

    #pragma unroll 4
    for (int k = 0; k < DD; ++k) {
        float4 x = sNF[k];
        float w1 = Ws1[k * DD + t];
        float w2 = Wv1[k * DD + t];
        float w3 = Wa1[k * DD + t];
        as.x = fmaf(x.x, w1, as.x); as.y = fmaf(x.y, w1, as.y);
        as.z = fmaf(x.z, w1, as.z); as.w = fmaf(x.w, w1, as.w);
        av.x = fmaf(x.x, w2, av.x); av.y = fmaf(x.y, w2, av.y);
        av.z = fmaf(x.z, w2, av.z); av.w = fmaf(x.w, w2, av.w);
        aa.x = fmaf(x.x, w3, aa.x); aa.y = fmaf(x.y, w3, aa.y);
        aa.z = fmaf(x.z, w3, aa.z); aa.w = fmaf(x.w, w3, aa.w);
    }

    // attention base rows (pre-activation)
    base_out[(r0 + 0) * DD + t] = aa.x;
    base_out[(r0 + 1) * DD + t] = aa.y;
    base_out[(r0 + 2) * DD + t] = aa.z;
    base_out[(r0 + 3) * DD + t] = aa.w;

    sHs[t] = make_float4(silu_f(as.x), silu_f(as.y), silu_f(as.z), silu_f(as.w));
    sHv[t] = make_float4(silu_f(av.x), silu_f(av.y), silu_f(av.z), silu_f(av.w));
    __syncthreads();

    // scalar branch layer 2 (full 128 cols)
    float4 os;
    { float b = bs2[t]; os = make_float4(b, b, b, b); }
    #pragma unroll 4
    for (int k = 0; k < DD; ++k) {
        float4 h = sHs[k];
        float w = Ws2[k * DD + t];
        os.x = fmaf(h.x, w, os.x); os.y = fmaf(h.y, w, os.y);
        os.z = fmaf(h.z, w, os.z); os.w = fmaf(h.w, w, os.w);
    }
    scalar_out[(r0 + 0) * DD + t] = os.x;
    scalar_out[(r0 + 1) * DD + t] = os.y;
    scalar_out[(r0 + 2) * DD + t] = os.z;
    scalar_out[(r0 + 3) * DD + t] = os.w;

    // vector branch layer 2: only 3 output cols used
    if (t < 12) {
        int r = t / 3, c = t % 3;
        const float* hv = (const float*)sHv;   // [k*4 + r]
        float a = bv2[c];
        for (int k = 0; k < DD; ++k) a = fmaf(hv[k * 4 + r], Wv2[k * DD + c], a);
        vf3_out[(r0 + r) * 3 + c] = a;
    }
}

// ---------------------------------------------------------------------------
// Kernel B: one block per (b,i), 128 threads, 4 j's per thread (fused in the
// inner loop so each LDS broadcast serves 16 elements). All softmax math in
// log2 units: weights pre-scaled by -log2e, a2 negated, exp via v_exp_f32.
// ---------------------------------------------------------------------------
__device__ __forceinline__ void step4(const float4 P, const float am,
                                      const float* __restrict__ f1,
                                      const float* __restrict__ f2,
                                      const float* __restrict__ f3,
                                      float* __restrict__ acc)
{
#pragma unroll
    for (int q = 0; q < 4; ++q) {
        // pre = -log2e * (base + d*w0 + dinv*w1 + dexp*w2)
        float pre = fmaf(f3[q], P.w, fmaf(f2[q], P.z, fmaf(f1[q], P.y, P.x)));
        float e   = exp2_hw(pre);                       // 2^pre = exp(-pre_nat)
        float r   = __builtin_amdgcn_rcpf(1.0f + e);    // sigmoid(pre_nat)
        acc[q]    = fmaf(pre * am, r, acc[q]);          // += log2e*silu*a2
    }
}

__global__ __launch_bounds__(128) void k_attn(
    const float* __restrict__ coords,
    const int*   __restrict__ mask,
    const float* __restrict__ Wa1,
    const float* __restrict__ Wa2,
    const float* __restrict__ ba2p,
    const float* __restrict__ base,
    const float* __restrict__ vf3,
    float* __restrict__ vec_out)
{
    __shared__ float4 s_pk[DD];      // (-l2e*base_t, -l2e*w0_t, -l2e*w1_t, -l2e*w2_t)
    __shared__ float  s_am[DD];      // -Wa2[t]
    __shared__ float  s_red[2][4];

    const int row = blockIdx.x;      // b*NN + i
    const int b   = row >> 9;
    const int tid = threadIdx.x;

    {
        float4 p;
        p.x = -LOG2E * base[row * DD + tid];
        p.y = -LOG2E * Wa1[128 * DD + tid];
        p.z = -LOG2E * Wa1[129 * DD + tid];
        p.w = -LOG2E * Wa1[130 * DD + tid];
        s_pk[tid] = p;
        s_am[tid] = -Wa2[tid];
    }
    __syncthreads();

    const float xi0 = coords[row * 3 + 0];
    const float xi1 = coords[row * 3 + 1];
    const float xi2 = coords[row * 3 + 2];
    const float* cb   = coords + (size_t)b * NN * 3;
    const int*   mrow = mask + (size_t)row * NN;
    const float  ba2l = ba2p[0] * LOG2E;

    float dx[4], dy[4], dz[4], f1[4], f2[4], f3[4], acc[4], lg[4];
    int mk[4];

    #pragma unroll
    for (int q = 0; q < 4; ++q) {
        const int j = tid + q * 128;
        mk[q] = mrow[j];
        dx[q] = xi0 - cb[j * 3 + 0];
        dy[q] = xi1 - cb[j * 3 + 1];
        dz[q] = xi2 - cb[j * 3 + 2];
        float d2 = fmaf(dx[q], dx[q], fmaf(dy[q], dy[q], dz[q] * dz[q]));
        float d  = sqrtf(d2);                    // d2>=0; sqrt(0)=0 matches ref
        f1[q] = d;
        float x = d + 1e-6f;
        float r = __builtin_amdgcn_rcpf(x);
        f2[q] = r * fmaf(-x, r, 2.0f);           // Newton: 1/(d+1e-6)
        f3[q] = exp2_hw(-LOG2E * d);             // exp(-d)
        acc[q] = ba2l;
    }

    const float4* am4 = (const float4*)s_am;
    for (int t4 = 0; t4 < DD / 4; ++t4) {
        float4 A  = am4[t4];
        float4 Pa = s_pk[t4 * 4 + 0];
        float4 Pb = s_pk[t4 * 4 + 1];
        float4 Pc = s_pk[t4 * 4 + 2];
        float4 Pd = s_pk[t4 * 4 + 3];
        step4(Pa, A.x, f1, f2, f3, acc);
        step4(Pb, A.y, f1, f2, f3, acc);
        step4(Pc, A.z, f1, f2, f3, acc);
        step4(Pd, A.w, f1, f2, f3, acc);
    }

    // logits (log2 units); masked -> -inf
    float m = -__builtin_inff();
    #pragma unroll
    for (int q = 0; q < 4; ++q) {
        lg[q] = mk[q] ? acc[q] : -__builtin_inff();
        m = fmaxf(m, lg[q]);
    }
    // wave max + cross-wave combine
    #pragma unroll
    for (int ofs = 32; ofs >= 1; ofs >>= 1) m = fmaxf(m, __shfl_xor(m, ofs));
    const int wid  = tid >> 6;
    const int lane = tid & 63;
    if (lane == 0) s_red[wid][0] = m;
    __syncthreads();
    const float mx = fmaxf(s_red[0][0], s_red[1][0]);
    __syncthreads();

    float es = 0.0f, wx = 0.0f, wy = 0.0f, wz = 0.0f;
    #pragma unroll
    for (int q = 0; q < 4; ++q) {
        if (mk[q]) {
            float e = exp2_hw(lg[q] - mx);
            es += e;
            wx = fmaf(e, dx[q], wx);
            wy = fmaf(e, dy[q], wy);
            wz = fmaf(e, dz[q], wz);
        }
    }
    #pragma unroll
    for (int ofs = 32; ofs >= 1; ofs >>= 1) {
        es += __shfl_xor(es, ofs);
        wx += __shfl_xor(wx, ofs);
        wy += __shfl_xor(wy, ofs);
        wz += __shfl_xor(wz, ofs);
    }
    if (lane == 0) {
        s_red[wid][0] = es; s_red[wid][1] = wx;
        s_red[wid][2] = wy; s_red[wid][3] = wz;
    }
    __syncthreads();
    if (tid < 3) {
        float tot = s_red[0][0] + s_red[1][0];
        float num = s_red[0][1 + tid] + s_red[1][1 + tid];
        vec_out[row * 3 + tid] = (num / tot) * vf3[row * 3 + tid];
    }
}

extern "C" void kernel_launch(void* const* d_in, const int* in_sizes, int n_in,
                              void* d_out, int out_size, void* d_ws, size_t ws_size,
                              hipStream_t stream) {
    const float* nf     = (const float*)d_in[0];
    const float* coords = (const float*)d_in[1];
    const int*   mask   = (const int*)  d_in[2];
    const float* Ws1 = (const float*)d_in[3];  const float* bs1 = (const float*)d_in[4];
    const float* Ws2 = (const float*)d_in[5];  const float* bs2 = (const float*)d_in[6];
    const float* Wv1 = (const float*)d_in[7];  const float* bv1 = (const float*)d_in[8];
    const float* Wv2 = (const float*)d_in[9];  const float* bv2 = (const float*)d_in[10];
    const float* Wa1 = (const float*)d_in[11]; const float* ba1 = (const float*)d_in[12];
    const float* Wa2 = (const float*)d_in[13]; const float* ba2 = (const float*)d_in[14];

    float* scalar_out = (float*)d_out;                       // [NB*NN*DD]
    float* vec_out    = (float*)d_out + NB * NN * DD;        // [NB*NN*3]
    float* base_ws    = (float*)d_ws;                        // [NB*NN*DD]
    float* vf3_ws     = (float*)d_ws + NB * NN * DD;         // [NB*NN*3]

    hipLaunchKernelGGL(k_node, dim3(NB * NN / 4), dim3(128), 0, stream,
                       nf, Ws1, bs1, Ws2, bs2, Wv1, bv1, Wv2, bv2, Wa1, ba1,
                       scalar_out, base_ws, vf3_ws);
    hipLaunchKernelGGL(k_attn, dim3(NB * NN), dim3(128), 0, stream,
                       coords, mask, Wa1, Wa2, ba2, base_ws, vf3_ws, vec_out);
}

// Round 4
// 33.707 us; speedup vs baseline: 1.4484x; 1.0745x over previous
//
#include <hip/hip_runtime.h>
#include <math.h>

#define NB 2
#define NN 512
#define DD 128
#define LOG2E 1.4426950408889634f

typedef unsigned long long ull;

__device__ __forceinline__ float exp2_hw(float x) {
    float r; asm("v_exp_f32 %0, %1" : "=v"(r) : "v"(x)); return r;
}
__device__ __forceinline__ float silu_f(float x) {
    float e = exp2_hw(-LOG2E * x);
    return x * __builtin_amdgcn_rcpf(1.0f + e);
}

// ---------------------------------------------------------------------------
// Kernel A (identical to the R2 version that passed timing): per-node GEMVs,
// 4 rows per block, 128 threads. Layer-1 fused across Ws1/Wv1/Wa1 so the
// float4 LDS broadcast of nf amortizes over 12 FMAs.
// ---------------------------------------------------------------------------
__global__ __launch_bounds__(128) void k_node(
    const float* __restrict__ nf,
    const float* __restrict__ Ws1, const float* __restrict__ bs1,
    const float* __restrict__ Ws2, const float* __restrict__ bs2,
    const float* __restrict__ Wv1, const float* __restrict__ bv1,
    const float* __restrict__ Wv2, const float* __restrict__ bv2,
    const float* __restrict__ Wa1, const float* __restrict__ ba1,
    float* __restrict__ scalar_out,
    float* __restrict__ base_out,
    float* __restrict__ vf3_out)
{
    __shared__ float4 sNF[DD];
    __shared__ float4 sHs[DD];
    __shared__ float4 sHv[DD];
    const int t  = threadIdx.x;
    const int r0 = blockIdx.x * 4;

    {
        float4 v;
        v.x = nf[(r0 + 0) * DD + t];
        v.y = nf[(r0 + 1) * DD + t];
        v.z = nf[(r0 + 2) * DD + t];
        v.w = nf[(r0 + 3) * DD + t];
        sNF[t] = v;
    }
    __syncthreads();

    float4 as, av, aa;
    { float b = bs1[t]; as = make_float4(b, b, b, b); }
    { float b = bv1[t]; av = make_float4(b, b, b, b); }
    { float b = ba1[t]; aa = make_float4(b, b, b, b); }

    #pragma unroll 4
    for (int k = 0; k < DD; ++k) {
        float4 x = sNF[k];
        float w1 = Ws1[k * DD + t];
        float w2 = Wv1[k * DD + t];
        float w3 = Wa1[k * DD + t];
        as.x = fmaf(x.x, w1, as.x); as.y = fmaf(x.y, w1, as.y);
        as.z = fmaf(x.z, w1, as.z); as.w = fmaf(x.w, w1, as.w);
        av.x = fmaf(x.x, w2, av.x); av.y = fmaf(x.y, w2, av.y);
        av.z = fmaf(x.z, w2, av.z); av.w = fmaf(x.w, w2, av.w);
        aa.x = fmaf(x.x, w3, aa.x); aa.y = fmaf(x.y, w3, aa.y);
        aa.z = fmaf(x.z, w3, aa.z); aa.w = fmaf(x.w, w3, aa.w);
    }

    base_out[(r0 + 0) * DD + t] = aa.x;
    base_out[(r0 + 1) * DD + t] = aa.y;
    base_out[(r0 + 2) * DD + t] = aa.z;
    base_out[(r0 + 3) * DD + t] = aa.w;

    sHs[t] = make_float4(silu_f(as.x), silu_f(as.y), silu_f(as.z), silu_f(as.w));
    sHv[t] = make_float4(silu_f(av.x), silu_f(av.y), silu_f(av.z), silu_f(av.w));
    __syncthreads();

    float4 os;
    { float b = bs2[t]; os = make_float4(b, b, b, b); }
    #pragma unroll 4
    for (int k = 0; k < DD; ++k) {
        float4 h = sHs[k];
        float w = Ws2[k * DD + t];
        os.x = fmaf(h.x, w, os.x); os.y = fmaf(h.y, w, os.y);
        os.z = fmaf(h.z, w, os.z); os.w = fmaf(h.w, w, os.w);
    }
    scalar_out[(r0 + 0) * DD + t] = os.x;
    scalar_out[(r0 + 1) * DD + t] = os.y;
    scalar_out[(r0 + 2) * DD + t] = os.z;
    scalar_out[(r0 + 3) * DD + t] = os.w;

    if (t < 12) {
        int r = t / 3, c = t % 3;
        const float* hv = (const float*)sHv;
        float a = bv2[c];
        for (int k = 0; k < DD; ++k) a = fmaf(hv[k * 4 + r], Wv2[k * DD + c], a);
        vf3_out[(r0 + r) * 3 + c] = a;
    }
}

// ---------------------------------------------------------------------------
// Kernel B: one block per (b,i), 256 threads. Deterministic mask compaction
// (ballot counts -> single-thread scan -> fixed per-wave offsets, NO atomics)
// halves the silu-dot work. Logits/diffs stay in registers across both
// softmax passes. All softmax math in log2 units.
// ---------------------------------------------------------------------------
__global__ __launch_bounds__(256) void k_attn(
    const float* __restrict__ coords,
    const int*   __restrict__ mask,
    const float* __restrict__ Wa1,
    const float* __restrict__ Wa2,
    const float* __restrict__ ba2p,
    const float* __restrict__ base,
    const float* __restrict__ vf3,
    float* __restrict__ vec_out)
{
    __shared__ float4 s_pk[DD];              // (-l2e*base, -l2e*w0, -l2e*w1, -l2e*w2)
    __shared__ float  s_am[DD];              // -Wa2
    __shared__ short  s_act[NN];
    __shared__ int    s_cnt8[8], s_off8[8], s_nactS;
    __shared__ float  s_red[4], s_red2[4][4];

    const int row  = blockIdx.x;             // b*NN + i
    const int b    = row >> 9;
    const int tid  = threadIdx.x;
    const int lane = tid & 63;
    const int wid  = tid >> 6;

    if (tid < DD) {
        float4 p;
        p.x = -LOG2E * base[row * DD + tid];
        p.y = -LOG2E * Wa1[128 * DD + tid];
        p.z = -LOG2E * Wa1[129 * DD + tid];
        p.w = -LOG2E * Wa1[130 * DD + tid];
        s_pk[tid] = p;
        s_am[tid] = -Wa2[tid];
    }

    // ---- deterministic compaction: j = tid and j = tid+256 ----
    const int* mrow = mask + (size_t)row * NN;
    const bool m0 = (mrow[tid]       != 0);
    const bool m1 = (mrow[tid + 256] != 0);
    const ull  b0 = __ballot(m0);
    const ull  b1 = __ballot(m1);
    if (lane == 0) {
        s_cnt8[wid]     = __popcll(b0);
        s_cnt8[4 + wid] = __popcll(b1);
    }
    __syncthreads();
    if (tid == 0) {
        int acc = 0;
        #pragma unroll
        for (int q = 0; q < 8; ++q) { s_off8[q] = acc; acc += s_cnt8[q]; }
        s_nactS = acc;
    }
    __syncthreads();
    {
        const ull lmask = (1ull << lane) - 1ull;
        if (m0) s_act[s_off8[wid]     + __popcll(b0 & lmask)] = (short)tid;
        if (m1) s_act[s_off8[4 + wid] + __popcll(b1 & lmask)] = (short)(tid + 256);
    }
    __syncthreads();
    const int nact = s_nactS;

    const float ba2l = ba2p[0] * LOG2E;
    const float xi0 = coords[row * 3 + 0];
    const float xi1 = coords[row * 3 + 1];
    const float xi2 = coords[row * 3 + 2];
    const float* cb = coords + (size_t)b * NN * 3;
    const float4* A4 = (const float4*)s_am;

    // ---- pass 1: logits for active pairs (round 0: a=tid, round 1: a=tid+256)
    float lg0 = 0.f, dx0 = 0.f, dy0 = 0.f, dz0 = 0.f;
    float lg1 = 0.f, dx1 = 0.f, dy1 = 0.f, dz1 = 0.f;
    const bool act0 = (tid < nact);
    const bool act1 = (tid + 256 < nact);

    if (act0) {
        int j = (int)s_act[tid];
        dx0 = xi0 - cb[j * 3 + 0];
        dy0 = xi1 - cb[j * 3 + 1];
        dz0 = xi2 - cb[j * 3 + 2];
        float d2 = fmaf(dx0, dx0, fmaf(dy0, dy0, dz0 * dz0));
        float d  = sqrtf(d2);
        float f1 = d;
        float x  = d + 1e-6f;
        float r0 = __builtin_amdgcn_rcpf(x);
        float f2 = r0 * fmaf(-x, r0, 2.0f);
        float f3 = exp2_hw(-LOG2E * d);
        float acc = ba2l;
        for (int t4 = 0; t4 < DD / 4; ++t4) {
            float4 A = A4[t4];
            { float4 P = s_pk[4*t4+0]; float pre = fmaf(f3,P.w,fmaf(f2,P.z,fmaf(f1,P.y,P.x)));
              float e = exp2_hw(pre); float r = __builtin_amdgcn_rcpf(1.0f+e);
              acc = fmaf(pre*A.x, r, acc); }
            { float4 P = s_pk[4*t4+1]; float pre = fmaf(f3,P.w,fmaf(f2,P.z,fmaf(f1,P.y,P.x)));
              float e = exp2_hw(pre); float r = __builtin_amdgcn_rcpf(1.0f+e);
              acc = fmaf(pre*A.y, r, acc); }
            { float4 P = s_pk[4*t4+2]; float pre = fmaf(f3,P.w,fmaf(f2,P.z,fmaf(f1,P.y,P.x)));
              float e = exp2_hw(pre); float r = __builtin_amdgcn_rcpf(1.0f+e);
              acc = fmaf(pre*A.z, r, acc); }
            { float4 P = s_pk[4*t4+3]; float pre = fmaf(f3,P.w,fmaf(f2,P.z,fmaf(f1,P.y,P.x)));
              float e = exp2_hw(pre); float r = __builtin_amdgcn_rcpf(1.0f+e);
              acc = fmaf(pre*A.w, r, acc); }
        }
        lg0 = acc;
    }
    if (act1) {
        int j = (int)s_act[tid + 256];
        dx1 = xi0 - cb[j * 3 + 0];
        dy1 = xi1 - cb[j * 3 + 1];
        dz1 = xi2 - cb[j * 3 + 2];
        float d2 = fmaf(dx1, dx1, fmaf(dy1, dy1, dz1 * dz1));
        float d  = sqrtf(d2);
        float f1 = d;
        float x  = d + 1e-6f;
        float r0 = __builtin_amdgcn_rcpf(x);
        float f2 = r0 * fmaf(-x, r0, 2.0f);
        float f3 = exp2_hw(-LOG2E * d);
        float acc = ba2l;
        for (int t4 = 0; t4 < DD / 4; ++t4) {
            float4 A = A4[t4];
            { float4 P = s_pk[4*t4+0]; float pre = fmaf(f3,P.w,fmaf(f2,P.z,fmaf(f1,P.y,P.x)));
              float e = exp2_hw(pre); float r = __builtin_amdgcn_rcpf(1.0f+e);
              acc = fmaf(pre*A.x, r, acc); }
            { float4 P = s_pk[4*t4+1]; float pre = fmaf(f3,P.w,fmaf(f2,P.z,fmaf(f1,P.y,P.x)));
              float e = exp2_hw(pre); float r = __builtin_amdgcn_rcpf(1.0f+e);
              acc = fmaf(pre*A.y, r, acc); }
            { float4 P = s_pk[4*t4+2]; float pre = fmaf(f3,P.w,fmaf(f2,P.z,fmaf(f1,P.y,P.x)));
              float e = exp2_hw(pre); float r = __builtin_amdgcn_rcpf(1.0f+e);
              acc = fmaf(pre*A.z, r, acc); }
            { float4 P = s_pk[4*t4+3]; float pre = fmaf(f3,P.w,fmaf(f2,P.z,fmaf(f1,P.y,P.x)));
              float e = exp2_hw(pre); float r = __builtin_amdgcn_rcpf(1.0f+e);
              acc = fmaf(pre*A.w, r, acc); }
        }
        lg1 = acc;
    }

    // ---- block max ----
    float mloc = -__builtin_inff();
    if (act0) mloc = lg0;
    if (act1) mloc = fmaxf(mloc, lg1);
    #pragma unroll
    for (int ofs = 32; ofs >= 1; ofs >>= 1) mloc = fmaxf(mloc, __shfl_xor(mloc, ofs));
    if (lane == 0) s_red[wid] = mloc;
    __syncthreads();
    const float mx = fmaxf(fmaxf(s_red[0], s_red[1]), fmaxf(s_red[2], s_red[3]));

    // ---- pass 2: exp + weighted diff (registers only) ----
    float es = 0.f, wx = 0.f, wy = 0.f, wz = 0.f;
    if (act0) {
        float e = exp2_hw(lg0 - mx);
        es += e; wx = fmaf(e, dx0, wx); wy = fmaf(e, dy0, wy); wz = fmaf(e, dz0, wz);
    }
    if (act1) {
        float e = exp2_hw(lg1 - mx);
        es += e; wx = fmaf(e, dx1, wx); wy = fmaf(e, dy1, wy); wz = fmaf(e, dz1, wz);
    }
    #pragma unroll
    for (int ofs = 32; ofs >= 1; ofs >>= 1) {
        es += __shfl_xor(es, ofs);
        wx += __shfl_xor(wx, ofs);
        wy += __shfl_xor(wy, ofs);
        wz += __shfl_xor(wz, ofs);
    }
    if (lane == 0) {
        s_red2[wid][0] = es; s_red2[wid][1] = wx;
        s_red2[wid][2] = wy; s_red2[wid][3] = wz;
    }
    __syncthreads();

    if (tid < 3) {
        float tot = s_red2[0][0] + s_red2[1][0] + s_red2[2][0] + s_red2[3][0];
        float num = s_red2[0][1+tid] + s_red2[1][1+tid] + s_red2[2][1+tid] + s_red2[3][1+tid];
        vec_out[row * 3 + tid] = (num / tot) * vf3[row * 3 + tid];
    }
}

extern "C" void kernel_launch(void* const* d_in, const int* in_sizes, int n_in,
                              void* d_out, int out_size, void* d_ws, size_t ws_size,
                              hipStream_t stream) {
    const float* nf     = (const float*)d_in[0];
    const float* coords = (const float*)d_in[1];
    const int*   mask   = (const int*)  d_in[2];
    const float* Ws1 = (const float*)d_in[3];  const float* bs1 = (const float*)d_in[4];
    const float* Ws2 = (const float*)d_in[5];  const float* bs2 = (const float*)d_in[6];
    const float* Wv1 = (const float*)d_in[7];  const float* bv1 = (const float*)d_in[8];
    const float* Wv2 = (const float*)d_in[9];  const float* bv2 = (const float*)d_in[10];
    const float* Wa1 = (const float*)d_in[11]; const float* ba1 = (const float*)d_in[12];
    const float* Wa2 = (const float*)d_in[13]; const float* ba2 = (const float*)d_in[14];

    float* scalar_out = (float*)d_out;                       // [NB*NN*DD]
    float* vec_out    = (float*)d_out + NB * NN * DD;        // [NB*NN*3]
    float* base_ws    = (float*)d_ws;                        // [NB*NN*DD]
    float* vf3_ws     = (float*)d_ws + NB * NN * DD;         // [NB*NN*3]

    hipLaunchKernelGGL(k_node, dim3(NB * NN / 4), dim3(128), 0, stream,
                       nf, Ws1, bs1, Ws2, bs2, Wv1, bv1, Wv2, bv2, Wa1, ba1,
                       scalar_out, base_ws, vf3_ws);
    hipLaunchKernelGGL(k_attn, dim3(NB * NN), dim3(256), 0, stream,
                       coords, mask, Wa1, Wa2, ba2, base_ws, vf3_ws, vec_out);
}

// Round 5
// 28.493 us; speedup vs baseline: 1.7134x; 1.1830x over previous
//
#include <hip/hip_runtime.h>
#include <math.h>

#define NB 2
#define NN 512
#define DD 128
#define LOG2E 1.4426950408889634f

typedef unsigned long long ull;

__device__ __forceinline__ float exp2_hw(float x) {
    float r; asm("v_exp_f32 %0, %1" : "=v"(r) : "v"(x)); return r;
}
__device__ __forceinline__ float silu_f(float x) {
    float e = exp2_hw(-LOG2E * x);
    return x * __builtin_amdgcn_rcpf(1.0f + e);
}

// ---------------------------------------------------------------------------
// One kernel, 1024 uniform blocks (one per (b,i) row), 256 threads.
// Per block: fused layer-1 GEMVs (Ws1/Wv1/Wa1, split-k), Ws2 GEMV -> scalar
// row, vf3 via 96-thread column split, then masked-softmax attention with
// deterministic (atomic-free) compaction. No cross-block deps, no workspace.
// ---------------------------------------------------------------------------
__global__ __launch_bounds__(256) void k_all(
    const float* __restrict__ nf,
    const float* __restrict__ coords,
    const int*   __restrict__ mask,
    const float* __restrict__ Ws1, const float* __restrict__ bs1,
    const float* __restrict__ Ws2, const float* __restrict__ bs2,
    const float* __restrict__ Wv1, const float* __restrict__ bv1,
    const float* __restrict__ Wv2, const float* __restrict__ bv2,
    const float* __restrict__ Wa1, const float* __restrict__ ba1,
    const float* __restrict__ Wa2, const float* __restrict__ ba2p,
    float* __restrict__ scalar_out,
    float* __restrict__ vec_out)
{
    __shared__ float  s_nf[DD];
    __shared__ float  s_part[3][256];
    __shared__ float  s_hs[DD];
    __shared__ float  s_hv[DD];
    __shared__ float4 s_pk[DD];              // (-l2e*base, -l2e*w0, -l2e*w1, -l2e*w2)
    __shared__ float  s_am[DD];              // -Wa2
    __shared__ short  s_act[NN];
    __shared__ int    s_cnt8[8], s_off8[8], s_nactS;
    __shared__ float  s_red[4], s_red2[4][4];

    const int row  = blockIdx.x;             // b*NN + i
    const int b    = row >> 9;
    const int tid  = threadIdx.x;
    const int lane = tid & 63;
    const int wid  = tid >> 6;
    const int c    = tid & 127;
    const int h    = tid >> 7;

    if (tid < DD) s_nf[tid] = nf[row * DD + tid];
    __syncthreads();

    // ---- phase A: fused layer-1 GEMVs (Ws1, Wv1, Wa1), split-k over h ----
    {
        float ps = 0.f, pv = 0.f, pa = 0.f;
        const int k0 = h * 64;
        #pragma unroll 8
        for (int kk = 0; kk < 64; ++kk) {
            int k   = k0 + kk;
            float x = s_nf[k];
            ps = fmaf(x, Ws1[k * DD + c], ps);
            pv = fmaf(x, Wv1[k * DD + c], pv);
            pa = fmaf(x, Wa1[k * DD + c], pa);
        }
        s_part[0][tid] = ps;
        s_part[1][tid] = pv;
        s_part[2][tid] = pa;
    }
    // ---- mask ballots (independent of LDS state) ----
    const int* mrow = mask + (size_t)row * NN;
    const bool m0 = (mrow[tid]       != 0);
    const bool m1 = (mrow[tid + 256] != 0);
    const ull  bal0 = __ballot(m0);
    const ull  bal1 = __ballot(m1);
    if (lane == 0) {
        s_cnt8[wid]     = __popcll(bal0);
        s_cnt8[4 + wid] = __popcll(bal1);
    }
    __syncthreads();   // s_part + s_cnt8 ready

    if (tid < DD) {
        s_hs[tid] = silu_f(s_part[0][tid] + s_part[0][128 + tid] + bs1[tid]);
        s_hv[tid] = silu_f(s_part[1][tid] + s_part[1][128 + tid] + bv1[tid]);
        float base = s_part[2][tid] + s_part[2][128 + tid] + ba1[tid];
        float4 p;
        p.x = -LOG2E * base;
        p.y = -LOG2E * Wa1[128 * DD + tid];
        p.z = -LOG2E * Wa1[129 * DD + tid];
        p.w = -LOG2E * Wa1[130 * DD + tid];
        s_pk[tid] = p;
        s_am[tid] = -Wa2[tid];
    }
    if (tid == 0) {
        int acc = 0;
        #pragma unroll
        for (int q = 0; q < 8; ++q) { s_off8[q] = acc; acc += s_cnt8[q]; }
        s_nactS = acc;
    }
    __syncthreads();   // s_hs/s_hv/s_pk/s_am/s_off8 ready; s_part free

    // ---- phase B: Ws2 @ s_hs (split-k), + vf3 partials on threads 128..223 --
    {
        float pb = 0.f;
        const int k0 = h * 64;
        #pragma unroll 8
        for (int kk = 0; kk < 64; ++kk) {
            int k = k0 + kk;
            pb = fmaf(s_hs[k], Ws2[k * DD + c], pb);
        }
        s_part[0][tid] = pb;
    }
    if (tid >= 128 && tid < 224) {
        int idx = tid - 128;
        int col = idx >> 5;          // 0..2
        int kq  = idx & 31;          // 0..31 -> k = 4*kq .. 4*kq+3
        float vp = 0.f;
        #pragma unroll
        for (int u = 0; u < 4; ++u) {
            int k = 4 * kq + u;
            vp = fmaf(s_hv[k], Wv2[k * DD + col], vp);
        }
        s_part[1][tid] = vp;
    }
    // compacted index writes (s_off8 ready)
    {
        const ull lmask = (1ull << lane) - 1ull;
        if (m0) s_act[s_off8[wid]     + __popcll(bal0 & lmask)] = (short)tid;
        if (m1) s_act[s_off8[4 + wid] + __popcll(bal1 & lmask)] = (short)(tid + 256);
    }
    __syncthreads();   // s_part[0], s_part[1] partials, s_act ready

    if (tid < DD) {
        scalar_out[row * DD + tid] = s_part[0][tid] + s_part[0][128 + tid] + bs2[tid];
    }
    float vf_col = 0.f;
    if (tid < 3) {
        float v = bv2[tid];
        const float* pp = &s_part[1][128 + tid * 32];
        for (int r = 0; r < 32; ++r) v += pp[r];
        vf_col = v;
    }
    const int nact = s_nactS;

    // ---- attention (R4-proven structure) ----
    const float ba2l = ba2p[0] * LOG2E;
    const float xi0 = coords[row * 3 + 0];
    const float xi1 = coords[row * 3 + 1];
    const float xi2 = coords[row * 3 + 2];
    const float* cb = coords + (size_t)b * NN * 3;
    const float4* A4 = (const float4*)s_am;

    float lg0 = 0.f, dx0 = 0.f, dy0 = 0.f, dz0 = 0.f;
    float lg1 = 0.f, dx1 = 0.f, dy1 = 0.f, dz1 = 0.f;
    const bool act0 = (tid < nact);
    const bool act1 = (tid + 256 < nact);

    if (act0) {
        int j = (int)s_act[tid];
        dx0 = xi0 - cb[j * 3 + 0];
        dy0 = xi1 - cb[j * 3 + 1];
        dz0 = xi2 - cb[j * 3 + 2];
        float d2 = fmaf(dx0, dx0, fmaf(dy0, dy0, dz0 * dz0));
        float d  = sqrtf(d2);
        float f1 = d;
        float x  = d + 1e-6f;
        float rc = __builtin_amdgcn_rcpf(x);
        float f2 = rc * fmaf(-x, rc, 2.0f);
        float f3 = exp2_hw(-LOG2E * d);
        float acc = ba2l;
        for (int t4 = 0; t4 < DD / 4; ++t4) {
            float4 A = A4[t4];
            { float4 P = s_pk[4*t4+0]; float pre = fmaf(f3,P.w,fmaf(f2,P.z,fmaf(f1,P.y,P.x)));
              float e = exp2_hw(pre); float r = __builtin_amdgcn_rcpf(1.0f+e);
              acc = fmaf(pre*A.x, r, acc); }
            { float4 P = s_pk[4*t4+1]; float pre = fmaf(f3,P.w,fmaf(f2,P.z,fmaf(f1,P.y,P.x)));
              float e = exp2_hw(pre); float r = __builtin_amdgcn_rcpf(1.0f+e);
              acc = fmaf(pre*A.y, r, acc); }
            { float4 P = s_pk[4*t4+2]; float pre = fmaf(f3,P.w,fmaf(f2,P.z,fmaf(f1,P.y,P.x)));
              float e = exp2_hw(pre); float r = __builtin_amdgcn_rcpf(1.0f+e);
              acc = fmaf(pre*A.z, r, acc); }
            { float4 P = s_pk[4*t4+3]; float pre = fmaf(f3,P.w,fmaf(f2,P.z,fmaf(f1,P.y,P.x)));
              float e = exp2_hw(pre); float r = __builtin_amdgcn_rcpf(1.0f+e);
              acc = fmaf(pre*A.w, r, acc); }
        }
        lg0 = acc;
    }
    if (act1) {
        int j = (int)s_act[tid + 256];
        dx1 = xi0 - cb[j * 3 + 0];
        dy1 = xi1 - cb[j * 3 + 1];
        dz1 = xi2 - cb[j * 3 + 2];
        float d2 = fmaf(dx1, dx1, fmaf(dy1, dy1, dz1 * dz1));
        float d  = sqrtf(d2);
        float f1 = d;
        float x  = d + 1e-6f;
        float rc = __builtin_amdgcn_rcpf(x);
        float f2 = rc * fmaf(-x, rc, 2.0f);
        float f3 = exp2_hw(-LOG2E * d);
        float acc = ba2l;
        for (int t4 = 0; t4 < DD / 4; ++t4) {
            float4 A = A4[t4];
            { float4 P = s_pk[4*t4+0]; float pre = fmaf(f3,P.w,fmaf(f2,P.z,fmaf(f1,P.y,P.x)));
              float e = exp2_hw(pre); float r = __builtin_amdgcn_rcpf(1.0f+e);
              acc = fmaf(pre*A.x, r, acc); }
            { float4 P = s_pk[4*t4+1]; float pre = fmaf(f3,P.w,fmaf(f2,P.z,fmaf(f1,P.y,P.x)));
              float e = exp2_hw(pre); float r = __builtin_amdgcn_rcpf(1.0f+e);
              acc = fmaf(pre*A.y, r, acc); }
            { float4 P = s_pk[4*t4+2]; float pre = fmaf(f3,P.w,fmaf(f2,P.z,fmaf(f1,P.y,P.x)));
              float e = exp2_hw(pre); float r = __builtin_amdgcn_rcpf(1.0f+e);
              acc = fmaf(pre*A.z, r, acc); }
            { float4 P = s_pk[4*t4+3]; float pre = fmaf(f3,P.w,fmaf(f2,P.z,fmaf(f1,P.y,P.x)));
              float e = exp2_hw(pre); float r = __builtin_amdgcn_rcpf(1.0f+e);
              acc = fmaf(pre*A.w, r, acc); }
        }
        lg1 = acc;
    }

    // ---- block max ----
    float mloc = -__builtin_inff();
    if (act0) mloc = lg0;
    if (act1) mloc = fmaxf(mloc, lg1);
    #pragma unroll
    for (int ofs = 32; ofs >= 1; ofs >>= 1) mloc = fmaxf(mloc, __shfl_xor(mloc, ofs));
    if (lane == 0) s_red[wid] = mloc;
    __syncthreads();
    const float mx = fmaxf(fmaxf(s_red[0], s_red[1]), fmaxf(s_red[2], s_red[3]));

    // ---- pass 2: exp + weighted diff (registers only) ----
    float es = 0.f, wx = 0.f, wy = 0.f, wz = 0.f;
    if (act0) {
        float e = exp2_hw(lg0 - mx);
        es += e; wx = fmaf(e, dx0, wx); wy = fmaf(e, dy0, wy); wz = fmaf(e, dz0, wz);
    }
    if (act1) {
        float e = exp2_hw(lg1 - mx);
        es += e; wx = fmaf(e, dx1, wx); wy = fmaf(e, dy1, wy); wz = fmaf(e, dz1, wz);
    }
    #pragma unroll
    for (int ofs = 32; ofs >= 1; ofs >>= 1) {
        es += __shfl_xor(es, ofs);
        wx += __shfl_xor(wx, ofs);
        wy += __shfl_xor(wy, ofs);
        wz += __shfl_xor(wz, ofs);
    }
    if (lane == 0) {
        s_red2[wid][0] = es; s_red2[wid][1] = wx;
        s_red2[wid][2] = wy; s_red2[wid][3] = wz;
    }
    __syncthreads();

    if (tid < 3) {
        float tot = s_red2[0][0] + s_red2[1][0] + s_red2[2][0] + s_red2[3][0];
        float num = s_red2[0][1+tid] + s_red2[1][1+tid] + s_red2[2][1+tid] + s_red2[3][1+tid];
        vec_out[row * 3 + tid] = (num / tot) * vf_col;
    }
}

extern "C" void kernel_launch(void* const* d_in, const int* in_sizes, int n_in,
                              void* d_out, int out_size, void* d_ws, size_t ws_size,
                              hipStream_t stream) {
    const float* nf     = (const float*)d_in[0];
    const float* coords = (const float*)d_in[1];
    const int*   mask   = (const int*)  d_in[2];
    const float* Ws1 = (const float*)d_in[3];  const float* bs1 = (const float*)d_in[4];
    const float* Ws2 = (const float*)d_in[5];  const float* bs2 = (const float*)d_in[6];
    const float* Wv1 = (const float*)d_in[7];  const float* bv1 = (const float*)d_in[8];
    const float* Wv2 = (const float*)d_in[9];  const float* bv2 = (const float*)d_in[10];
    const float* Wa1 = (const float*)d_in[11]; const float* ba1 = (const float*)d_in[12];
    const float* Wa2 = (const float*)d_in[13]; const float* ba2 = (const float*)d_in[14];

    float* scalar_out = (float*)d_out;                   // [NB*NN*DD]
    float* vec_out    = (float*)d_out + NB * NN * DD;    // [NB*NN*3]

    hipLaunchKernelGGL(k_all, dim3(NB * NN), dim3(256), 0, stream,
                       nf, coords, mask,
                       Ws1, bs1, Ws2, bs2, Wv1, bv1, Wv2, bv2,
                       Wa1, ba1, Wa2, ba2,
                       scalar_out, vec_out);
}